// Round 8
// baseline (154.396 us; speedup 1.0000x reference)
//
#include <hip/hip_runtime.h>
#include <stdint.h>

#define EPS 1e-5f

typedef float f32x4 __attribute__((ext_vector_type(4)));
typedef float f32x16 __attribute__((ext_vector_type(16)));
typedef __bf16 bf16x8 __attribute__((ext_vector_type(8)));
typedef uint32_t u32x4 __attribute__((ext_vector_type(4)));

__device__ __forceinline__ ushort f2bf(float f){
  union { float f; uint32_t u; } v; v.f = f;
  uint32_t r = v.u + 0x7fffu + ((v.u >> 16) & 1u);
  return (ushort)(r >> 16);
}

__device__ __forceinline__ float bf2f(ushort u){
  union { uint32_t u; float f; } v; v.u = ((uint32_t)u) << 16;
  return v.f;
}

__device__ __forceinline__ uint32_t pk2bf(float a, float b){
  __bf16 x = (__bf16)a, y = (__bf16)b;
  return (uint32_t)__builtin_bit_cast(ushort, x) |
         ((uint32_t)__builtin_bit_cast(ushort, y) << 16);
}

__device__ __forceinline__ f32x4 mfma16(bf16x8 a, bf16x8 b, f32x4 c){
  return __builtin_amdgcn_mfma_f32_16x16x32_bf16(a, b, c, 0, 0, 0);
}
__device__ __forceinline__ f32x16 mfma32(bf16x8 a, bf16x8 b, f32x16 c){
  return __builtin_amdgcn_mfma_f32_32x32x16_bf16(a, b, c, 0, 0, 0);
}

// ---------------- fused: weight cast + groupnorm stats stage 1 ----------------
__global__ __launch_bounds__(256) void k_pg(const float* wq, const float* wp, const float* x,
                                            ushort* wqb, ushort* wpb, float2* part){
  __shared__ float red[8];
  int bid = blockIdx.x;
  if (bid < 768){
    int i = bid * 256 + threadIdx.x;
    if (i < 3*256*256) wqb[i] = f2bf(wq[i]);
    if (i < 256*256)   wpb[i] = f2bf(wp[i]);
    return;
  }
  int gb = bid - 768;
  int bg = gb >> 6, pb = gb & 63;
  const f32x4* base = (const f32x4*)(x + (size_t)bg*131072 + (size_t)pb*2048);
  float s = 0.f, ss = 0.f;
  #pragma unroll
  for (int it = 0; it < 2; ++it){
    f32x4 v = base[threadIdx.x + it*256];
    #pragma unroll
    for (int j = 0; j < 4; ++j){ s += v[j]; ss += v[j]*v[j]; }
  }
  #pragma unroll
  for (int off = 1; off < 64; off <<= 1){
    s  += __shfl_xor(s,  off);
    ss += __shfl_xor(ss, off);
  }
  int wid = threadIdx.x >> 6;
  if ((threadIdx.x & 63) == 0){ red[wid] = s; red[4 + wid] = ss; }
  __syncthreads();
  if (threadIdx.x == 0){
    part[gb] = make_float2(red[0]+red[1]+red[2]+red[3],
                           red[4]+red[5]+red[6]+red[7]);
  }
}

// ---------------- fused GN finish + normalize + QKV GEMM -> FRAGMENT layouts ----
// Qf/Kf[bh][t32:128][dsub:4][lane:64][8]   (K rows bit2<->3 permuted; Q pre-scaled
// by 0.125*log2e so QK^T lands directly in exp2 domain)
// Vf[bh][kb:64][dt:2][c4:4][lane:64][8]
// grid (128 nt-of-32, 2 b) x 512
__global__ __launch_bounds__(512) void k_nqkv(const float* x, const float* gamma, const float* beta,
                                              const float2* part, const ushort* wqb, const float* bqkv,
                                              ushort* Qf, ushort* Kf, ushort* Vf){
  __shared__ ushort A[32][264];      // [n][c]
  __shared__ ushort Cl[32][136];     // Q/K slabs: [n][o_local]
  __shared__ ushort Cl_T[128][40];   // V slabs:   [o_local][n]
  __shared__ float2 st[8];
  const float SCL2 = 0.125f * 1.44269504f;
  int nt = blockIdx.x, b = blockIdx.y;
  int t = threadIdx.x, lane = t & 63, wid = t >> 6;

  // finish GN stats (8 waves x 8 groups)
  {
    float2 p = part[(b*8 + wid)*64 + lane];
    float s = p.x, ss = p.y;
    #pragma unroll
    for (int off = 1; off < 64; off <<= 1){
      s  += __shfl_xor(s,  off);
      ss += __shfl_xor(ss, off);
    }
    if (lane == 0){
      const float inv = 1.f / 131072.f;
      float mean = s * inv;
      float var  = ss * inv - mean*mean;
      st[wid] = make_float2(mean, rsqrtf(var + EPS));
    }
  }
  __syncthreads();

  // normalize x-tile [256c x 32n] -> A[n][c] bf16
  {
    int c = t >> 1, nh = t & 1;
    float2 s0 = st[c >> 5];
    float g  = gamma[c] * s0.y;
    float bt = beta[c] - s0.x * g;
    const float* xr = x + ((size_t)(b*256 + c))*4096 + nt*32 + nh*16;
    #pragma unroll
    for (int j4 = 0; j4 < 4; ++j4){
      f32x4 v = *(const f32x4*)(xr + j4*4);
      #pragma unroll
      for (int e = 0; e < 4; ++e) A[nh*16 + j4*4 + e][c] = f2bf(v[e]*g + bt);
    }
  }
  __syncthreads();

  // GEMM: C[32n x 768o] = A x W^T
  int l15 = lane & 15, g4 = lane >> 4;
  f32x4 acc[6][2];
  #pragma unroll
  for (int of = 0; of < 6; ++of)
    #pragma unroll
    for (int mf = 0; mf < 2; ++mf) acc[of][mf] = (f32x4){0.f,0.f,0.f,0.f};

  #pragma unroll
  for (int ks = 0; ks < 8; ++ks){
    bf16x8 a0 = *(const bf16x8*)&A[l15][ks*32 + g4*8];
    bf16x8 a1 = *(const bf16x8*)&A[16 + l15][ks*32 + g4*8];
    #pragma unroll
    for (int of = 0; of < 6; ++of){
      int o = of*128 + wid*16 + l15;
      bf16x8 bw = *(const bf16x8*)(wqb + (size_t)o*256 + ks*32 + g4*8);
      acc[of][0] = mfma16(a0, bw, acc[of][0]);
      acc[of][1] = mfma16(a1, bw, acc[of][1]);
    }
  }

  // epilogue: per 128-o slab, stage in LDS, write fragment layouts
  #pragma unroll
  for (int of = 0; of < 6; ++of){
    __syncthreads();
    float bias = bqkv[of*128 + wid*16 + l15];
    if (of < 4){
      float scl = (of < 2) ? SCL2 : 1.f;   // Q slabs pre-scaled into exp2 domain
      #pragma unroll
      for (int mf = 0; mf < 2; ++mf)
        #pragma unroll
        for (int r = 0; r < 4; ++r)
          Cl[mf*16 + g4*4 + r][wid*16 + l15] = f2bf((acc[of][mf][r] + bias) * scl);
    } else {
      #pragma unroll
      for (int mf = 0; mf < 2; ++mf)
        *(uint2*)&Cl_T[wid*16 + l15][mf*16 + g4*4] =
          make_uint2(pk2bf(acc[of][mf][0]+bias, acc[of][mf][1]+bias),
                     pk2bf(acc[of][mf][2]+bias, acc[of][mf][3]+bias));
    }
    __syncthreads();

    int hp = t >> 8;                       // head-half within slab
    int hh = (of & 1)*2 + hp;
    if (of < 4){
      int rem = t & 255, dsub = rem >> 6, ln = rem & 63, h2 = ln >> 5, p31 = ln & 31;
      int row = (of < 2) ? p31 : ((p31 & 19) | ((p31 & 4) << 1) | ((p31 & 8) >> 1));
      ushort* basep = (of < 2) ? Qf : Kf;
      uint4 v = *(const uint4*)&Cl[row][hp*64 + dsub*16 + h2*8];
      *(uint4*)(basep + ((size_t)(b*4 + hh))*262144 + nt*2048 + dsub*512 + ln*8) = v;
    } else {
      int rem = t & 255, dt = rem >> 7, r2 = rem & 127, c4h = r2 >> 5, p31 = r2 & 31;
      int c4 = (nt & 1)*2 + (c4h >> 1), h2 = c4h & 1;
      int n0 = (c4h >> 1)*16 + h2*8;
      int ln = h2*32 + p31;
      uint4 v = *(const uint4*)&Cl_T[hp*64 + dt*32 + p31][n0];
      *(uint4*)(Vf + ((size_t)(b*4 + hh))*262144 + (size_t)(nt >> 1)*4096
                   + dt*2048 + c4*512 + ln*8) = v;
    }
  }
}

// ---------------- flash attention: frag-layout streaming loads ----------------
// grid 8bh * 32qg * SPLIT x 256 (4 INDEPENDENT waves per block — no barriers/LDS;
// packed 4-to-a-block to dodge the per-CU workgroup-slot limit). bh pinned per XCD.
template<int SPLIT>
__global__ __launch_bounds__(256, 3) void k_attn(const ushort* Qf, const ushort* Kf,
                                                 const ushort* Vf, ushort* Opart, float2* ML){
  int bh = blockIdx.x & 7;
  int within = blockIdx.x >> 3;              // [0, 32*SPLIT)
  int sp = within >> 5, qg = within & 31;
  int t = threadIdx.x, wid = t >> 6, l = t & 63, l31 = l & 31, hi = l >> 5;
  int qt = qg*4 + wid;                       // 32-row q tile index [0,128)

  const ushort* Qg = Qf + (size_t)bh*262144 + qt*2048 + l*8;
  const ushort* Kg = Kf + (size_t)bh*262144 + l*8;
  const ushort* Vg = Vf + (size_t)bh*262144 + l*8;

  bf16x8 qf[4];
  #pragma unroll
  for (int dsub = 0; dsub < 4; ++dsub)
    qf[dsub] = *(const bf16x8*)(Qg + dsub*512);

  f32x16 o[2];   // [dt]  O^T[d][q]
  #pragma unroll
  for (int dt = 0; dt < 2; ++dt)
    #pragma unroll
    for (int r = 0; r < 16; ++r) o[dt][r] = 0.f;
  float m_s = -INFINITY, l_s = 0.f;

  const int kbBeg = sp * (64 / SPLIT), kbEnd = kbBeg + 64 / SPLIT;
  for (int kb = kbBeg; kb < kbEnd; ++kb){
    // K frags (streaming: each load = 1KB contiguous)
    bf16x8 kf[2][4];
    #pragma unroll
    for (int kt = 0; kt < 2; ++kt)
      #pragma unroll
      for (int dsub = 0; dsub < 4; ++dsub)
        kf[kt][dsub] = *(const bf16x8*)(Kg + (size_t)(kb*2 + kt)*2048 + dsub*512);

    // V frags (issue early; independent of softmax)
    bf16x8 vf[2][4];
    #pragma unroll
    for (int dt = 0; dt < 2; ++dt)
      #pragma unroll
      for (int c4 = 0; c4 < 4; ++c4)
        vf[dt][c4] = *(const bf16x8*)(Vg + (size_t)kb*4096 + dt*2048 + c4*512);

    // QK: S^T[kv][q]  (already exp2-domain; Q pre-scaled)
    f32x16 s[2];
    __builtin_amdgcn_s_setprio(1);
    #pragma unroll
    for (int kt = 0; kt < 2; ++kt){
      f32x16 acc;
      #pragma unroll
      for (int r = 0; r < 16; ++r) acc[r] = 0.f;
      #pragma unroll
      for (int dsub = 0; dsub < 4; ++dsub)
        acc = mfma32(kf[kt][dsub], qf[dsub], acc);
      s[kt] = acc;
    }
    __builtin_amdgcn_s_setprio(0);

    // softmax (q lane-local; only cross-lane partner is l^32)
    f32x16 mx = s[0];
    #pragma unroll
    for (int r = 0; r < 16; ++r) mx[r] = fmaxf(mx[r], s[1][r]);
    #pragma unroll
    for (int off = 8; off > 0; off >>= 1)
      #pragma unroll
      for (int r = 0; r < off; ++r) mx[r] = fmaxf(mx[r], mx[r + off]);
    float vm = fmaxf(mx[0], __shfl_xor(mx[0], 32));

    if (__any(vm > m_s + 8.f)){
      float mn = fmaxf(m_s, vm);
      float a = __builtin_amdgcn_exp2f(m_s - mn);
      m_s = mn; l_s *= a;
      #pragma unroll
      for (int dt = 0; dt < 2; ++dt)
        #pragma unroll
        for (int r = 0; r < 16; ++r) o[dt][r] *= a;
    }
    {
      float r0 = 0.f, r1 = 0.f, r2 = 0.f, r3 = 0.f;
      #pragma unroll
      for (int kt = 0; kt < 2; ++kt)
        #pragma unroll
        for (int r = 0; r < 16; r += 4){
          float e0 = __builtin_amdgcn_exp2f(s[kt][r+0] - m_s);
          float e1 = __builtin_amdgcn_exp2f(s[kt][r+1] - m_s);
          float e2 = __builtin_amdgcn_exp2f(s[kt][r+2] - m_s);
          float e3 = __builtin_amdgcn_exp2f(s[kt][r+3] - m_s);
          s[kt][r+0] = e0; s[kt][r+1] = e1;
          s[kt][r+2] = e2; s[kt][r+3] = e3;
          r0 += e0; r1 += e1; r2 += e2; r3 += e3;
        }
      float rr = (r0 + r1) + (r2 + r3);
      rr += __shfl_xor(rr, 32);
      l_s += rr;
    }

    // P -> bf16 B-frags (pure in-lane thanks to baked K-row permutation)
    bf16x8 pf[2][2];   // [kt][ks]
    #pragma unroll
    for (int kt = 0; kt < 2; ++kt)
      #pragma unroll
      for (int ks = 0; ks < 2; ++ks){
        u32x4 w;
        #pragma unroll
        for (int c = 0; c < 4; ++c)
          w[c] = pk2bf(s[kt][8*ks + 2*c], s[kt][8*ks + 2*c + 1]);
        pf[kt][ks] = __builtin_bit_cast(bf16x8, w);
      }

    // PV: O^T[d][q]
    __builtin_amdgcn_s_setprio(1);
    #pragma unroll
    for (int dt = 0; dt < 2; ++dt)
      #pragma unroll
      for (int kt = 0; kt < 2; ++kt)
        #pragma unroll
        for (int ks = 0; ks < 2; ++ks)
          o[dt] = mfma32(vf[dt][kt*2 + ks], pf[kt][ks], o[dt]);
    __builtin_amdgcn_s_setprio(0);
  }

  // epilogue: raw partial O [pw][32n][64d] + (m,l)
  int pw = (bh*SPLIT + sp)*128 + qt;
  if (hi == 0) ML[(size_t)pw*32 + l31] = make_float2(m_s, l_s);
  ushort* dst = Opart + (size_t)pw*2048;
  #pragma unroll
  for (int dt = 0; dt < 2; ++dt)
    #pragma unroll
    for (int rq = 0; rq < 4; ++rq){
      int d0 = dt*32 + rq*8 + 4*hi;
      uint2 w = make_uint2(pk2bf(o[dt][rq*4+0], o[dt][rq*4+1]),
                           pk2bf(o[dt][rq*4+2], o[dt][rq*4+3]));
      *(uint2*)(dst + (size_t)l31*64 + d0) = w;
    }
}

// ---------------- fused combine + proj GEMM + bias + residual ----------------
// grid (128 nt-of-32, 2 b) x 256
template<int SPLIT>
__global__ __launch_bounds__(256) void k_cproj(const ushort* Opart, const float2* ML,
                                               const ushort* wpb, const float* bproj,
                                               const float* x, float* out){
  __shared__ ushort A[32][264];
  int nt = blockIdx.x, b = blockIdx.y;
  int t = threadIdx.x;

  int n_local = t >> 3, d0 = (t & 7) * 8;
  #pragma unroll
  for (int h = 0; h < 4; ++h){
    int bh = b*4 + h;
    float2 mls[SPLIT];
    float m = -INFINITY;
    #pragma unroll
    for (int sp = 0; sp < SPLIT; ++sp){
      mls[sp] = ML[((size_t)((bh*SPLIT + sp)*128 + nt))*32 + n_local];
      m = fmaxf(m, mls[sp].x);
    }
    float den = 0.f, w[SPLIT];
    #pragma unroll
    for (int sp = 0; sp < SPLIT; ++sp){
      w[sp] = __builtin_amdgcn_exp2f(mls[sp].x - m);
      den += mls[sp].y * w[sp];
    }
    float inv = 1.f / den;
    float vals[8];
    #pragma unroll
    for (int j = 0; j < 8; ++j) vals[j] = 0.f;
    #pragma unroll
    for (int sp = 0; sp < SPLIT; ++sp){
      const ushort* src = Opart + ((size_t)((bh*SPLIT + sp)*128 + nt))*2048 + (size_t)n_local*64 + d0;
      uint4 a0 = *(const uint4*)src;
      float f = w[sp] * inv;
      #pragma unroll
      for (int j = 0; j < 8; ++j) vals[j] += bf2f(((const ushort*)&a0)[j]) * f;
    }
    uint32_t pk[4];
    #pragma unroll
    for (int j = 0; j < 4; ++j) pk[j] = pk2bf(vals[2*j], vals[2*j+1]);
    *(uint4*)&A[n_local][h*64 + d0] = make_uint4(pk[0], pk[1], pk[2], pk[3]);
  }
  __syncthreads();

  int lane = t & 63, wid = t >> 6, l15 = lane & 15, g4 = lane >> 4;
  f32x4 acc[4][2];     // [of][mf]
  #pragma unroll
  for (int of = 0; of < 4; ++of)
    #pragma unroll
    for (int mf = 0; mf < 2; ++mf) acc[of][mf] = (f32x4){0.f,0.f,0.f,0.f};

  #pragma unroll
  for (int ks = 0; ks < 8; ++ks){
    bf16x8 aa0 = *(const bf16x8*)&A[l15][ks*32 + g4*8];
    bf16x8 aa1 = *(const bf16x8*)&A[16 + l15][ks*32 + g4*8];
    #pragma unroll
    for (int of = 0; of < 4; ++of){
      int o = wid*64 + of*16 + l15;
      bf16x8 bw = *(const bf16x8*)(wpb + (size_t)o*256 + ks*32 + g4*8);
      acc[of][0] = mfma16(aa0, bw, acc[of][0]);
      acc[of][1] = mfma16(aa1, bw, acc[of][1]);
    }
  }

  #pragma unroll
  for (int of = 0; of < 4; ++of){
    int o = wid*64 + of*16 + l15;
    float bias = bproj[o];
    size_t cbase = ((size_t)b*256 + o)*4096;
    #pragma unroll
    for (int mf = 0; mf < 2; ++mf){
      int n0 = nt*32 + mf*16 + g4*4;
      f32x4 res = *(const f32x4*)(x + cbase + n0);
      f32x4 ov;
      #pragma unroll
      for (int r = 0; r < 4; ++r) ov[r] = acc[of][mf][r] + bias + res[r];
      *(f32x4*)(out + cbase + n0) = ov;
    }
  }
}

extern "C" void kernel_launch(void* const* d_in, const int* in_sizes, int n_in,
                              void* d_out, int out_size, void* d_ws, size_t ws_size,
                              hipStream_t stream) {
  const float* x     = (const float*)d_in[0];
  const float* gamma = (const float*)d_in[1];
  const float* beta  = (const float*)d_in[2];
  const float* wqkv  = (const float*)d_in[3];
  const float* bqkv  = (const float*)d_in[4];
  const float* wproj = (const float*)d_in[5];
  const float* bproj = (const float*)d_in[6];
  float* out = (float*)d_out;

  const size_t MiB = 1024*1024;
  char* ws = (char*)d_ws;
  float2* part   = (float2*)(ws + 0);            // 8 KB
  ushort* wq_b   = (ushort*)(ws + 16384);        // 384 KB
  ushort* wp_b   = (ushort*)(ws + 409600);       // 128 KB
  ushort* Qf     = (ushort*)(ws + 1*MiB);        // 4 MiB  frag layout (pre-scaled)
  ushort* Kf     = (ushort*)(ws + 5*MiB);        // 4 MiB  frag layout (rows permuted)
  ushort* Vf     = (ushort*)(ws + 9*MiB);        // 4 MiB  frag layout
  ushort* Opart  = (ushort*)(ws + 13*MiB);       // 4*SPLIT MiB  [pw][32n][64d]

  int split = (ws_size >= 31*MiB) ? 4 : 2;
  float2* ML = (float2*)(ws + (13 + 4*(size_t)split)*MiB);

  k_pg  <<<1792, 256, 0, stream>>>(wqkv, wproj, x, wq_b, wp_b, part);
  k_nqkv<<<dim3(128,2), 512, 0, stream>>>(x, gamma, beta, part, wq_b, bqkv, Qf, Kf, Vf);
  if (split == 4){
    k_attn<4><<<1024, 256, 0, stream>>>(Qf, Kf, Vf, Opart, ML);
    k_cproj<4><<<dim3(128,2), 256, 0, stream>>>(Opart, ML, wp_b, bproj, x, out);
  } else {
    k_attn<2><<<512, 256, 0, stream>>>(Qf, Kf, Vf, Opart, ML);
    k_cproj<2><<<dim3(128,2), 256, 0, stream>>>(Opart, ML, wp_b, bproj, x, out);
  }
}

// Round 9
// 153.586 us; speedup vs baseline: 1.0053x; 1.0053x over previous
//
#include <hip/hip_runtime.h>
#include <stdint.h>

#define EPS 1e-5f

typedef float f32x4 __attribute__((ext_vector_type(4)));
typedef float f32x16 __attribute__((ext_vector_type(16)));
typedef __bf16 bf16x8 __attribute__((ext_vector_type(8)));
typedef uint32_t u32x4 __attribute__((ext_vector_type(4)));

__device__ __forceinline__ ushort f2bf(float f){
  union { float f; uint32_t u; } v; v.f = f;
  uint32_t r = v.u + 0x7fffu + ((v.u >> 16) & 1u);
  return (ushort)(r >> 16);
}

__device__ __forceinline__ float bf2f(ushort u){
  union { uint32_t u; float f; } v; v.u = ((uint32_t)u) << 16;
  return v.f;
}

__device__ __forceinline__ uint32_t pk2bf(float a, float b){
  __bf16 x = (__bf16)a, y = (__bf16)b;
  return (uint32_t)__builtin_bit_cast(ushort, x) |
         ((uint32_t)__builtin_bit_cast(ushort, y) << 16);
}

__device__ __forceinline__ f32x4 mfma16(bf16x8 a, bf16x8 b, f32x4 c){
  return __builtin_amdgcn_mfma_f32_16x16x32_bf16(a, b, c, 0, 0, 0);
}
__device__ __forceinline__ f32x16 mfma32(bf16x8 a, bf16x8 b, f32x16 c){
  return __builtin_amdgcn_mfma_f32_32x32x16_bf16(a, b, c, 0, 0, 0);
}

// ---------------- fused: weight cast + groupnorm stats stage 1 ----------------
__global__ __launch_bounds__(256) void k_pg(const float* wq, const float* wp, const float* x,
                                            ushort* wqb, ushort* wpb, float2* part){
  __shared__ float red[8];
  int bid = blockIdx.x;
  if (bid < 768){
    int i = bid * 256 + threadIdx.x;
    if (i < 3*256*256) wqb[i] = f2bf(wq[i]);
    if (i < 256*256)   wpb[i] = f2bf(wp[i]);
    return;
  }
  int gb = bid - 768;
  int bg = gb >> 6, pb = gb & 63;
  const f32x4* base = (const f32x4*)(x + (size_t)bg*131072 + (size_t)pb*2048);
  float s = 0.f, ss = 0.f;
  #pragma unroll
  for (int it = 0; it < 2; ++it){
    f32x4 v = base[threadIdx.x + it*256];
    #pragma unroll
    for (int j = 0; j < 4; ++j){ s += v[j]; ss += v[j]*v[j]; }
  }
  #pragma unroll
  for (int off = 1; off < 64; off <<= 1){
    s  += __shfl_xor(s,  off);
    ss += __shfl_xor(ss, off);
  }
  int wid = threadIdx.x >> 6;
  if ((threadIdx.x & 63) == 0){ red[wid] = s; red[4 + wid] = ss; }
  __syncthreads();
  if (threadIdx.x == 0){
    part[gb] = make_float2(red[0]+red[1]+red[2]+red[3],
                           red[4]+red[5]+red[6]+red[7]);
  }
}

// ---------------- GN finish + normalize + transpose: x -> Xn[b][n][c] bf16 ----
// grid (64 nt-of-64n, 4 ct-of-64c, 2 b) x 256
__global__ __launch_bounds__(256) void k_norm(const float* x, const float* gamma, const float* beta,
                                              const float2* part, ushort* Xn){
  __shared__ float T[64][65];
  __shared__ float2 st[2];
  int nt = blockIdx.x, ct = blockIdx.y, b = blockIdx.z;
  int t = threadIdx.x, wid = t >> 6, ln = t & 63;

  if (wid < 2){
    float2 p = part[((b*8) + ct*2 + wid)*64 + ln];
    float s = p.x, ss = p.y;
    #pragma unroll
    for (int off = 1; off < 64; off <<= 1){
      s  += __shfl_xor(s,  off);
      ss += __shfl_xor(ss, off);
    }
    if (ln == 0){
      const float inv = 1.f / 131072.f;
      float mean = s * inv;
      float var  = ss * inv - mean*mean;
      st[wid] = make_float2(mean, rsqrtf(var + EPS));
    }
  }
  __syncthreads();

  int c_local = t >> 2, col0 = (t & 3) * 16;
  float2 s0 = st[c_local >> 5];
  float g  = gamma[ct*64 + c_local] * s0.y;
  float bt = beta[ct*64 + c_local] - s0.x * g;
  const float* xr = x + ((size_t)(b*256 + ct*64 + c_local))*4096 + nt*64 + col0;
  #pragma unroll
  for (int j = 0; j < 4; ++j){
    f32x4 v = *(const f32x4*)(xr + j*4);
    #pragma unroll
    for (int e = 0; e < 4; ++e) T[col0 + j*4 + e][c_local] = v[e]*g + bt;
  }
  __syncthreads();

  int n_local = t >> 2, c0 = (t & 3) * 16;
  uint32_t pk[8];
  #pragma unroll
  for (int j = 0; j < 8; ++j) pk[j] = pk2bf(T[n_local][c0 + 2*j], T[n_local][c0 + 2*j + 1]);
  ushort* dst = Xn + ((size_t)b*4096 + nt*64 + n_local)*256 + ct*64 + c0;
  *(uint4*)dst       = make_uint4(pk[0], pk[1], pk[2], pk[3]);
  *(uint4*)(dst + 8) = make_uint4(pk[4], pk[5], pk[6], pk[7]);
}

// ---------------- QKV GEMM from Xn -> FRAGMENT layouts ----------------
// Qf/Kf[bh][t32:128][dsub:4][lane:64][8] (K rows bit2<->3 permuted; Q pre-scaled)
// Vf[bh][kb:64][dt:2][c4:4][lane:64][8]
// grid (128 nt-of-32n, 3 typ, 2 b) x 256
__global__ __launch_bounds__(256) void k_qkv(const ushort* Xn, const ushort* wqb, const float* bqkv,
                                             ushort* Qf, ushort* Kf, ushort* Vf){
  __shared__ ushort SB[10240];     // Q/K: [32][264]=8448; V: [256][40]=10240
  const float SCL2 = 0.125f * 1.44269504f;
  int nt = blockIdx.x, typ = blockIdx.y, b = blockIdx.z;
  int t = threadIdx.x, lane = t & 63, wid = t >> 6, l15 = lane & 15, g4 = lane >> 4;

  f32x4 acc[4][2];   // [of][mf]
  #pragma unroll
  for (int of = 0; of < 4; ++of)
    #pragma unroll
    for (int mf = 0; mf < 2; ++mf) acc[of][mf] = (f32x4){0.f,0.f,0.f,0.f};

  const ushort* Ab = Xn + ((size_t)b*4096 + nt*32)*256;
  #pragma unroll
  for (int ks = 0; ks < 8; ++ks){
    bf16x8 aa0 = *(const bf16x8*)(Ab + (size_t)l15*256 + ks*32 + g4*8);
    bf16x8 aa1 = *(const bf16x8*)(Ab + (size_t)(16 + l15)*256 + ks*32 + g4*8);
    #pragma unroll
    for (int of = 0; of < 4; ++of){
      int ol = wid*64 + of*16 + l15;
      bf16x8 bw = *(const bf16x8*)(wqb + ((size_t)typ*256 + ol)*256 + ks*32 + g4*8);
      acc[of][0] = mfma16(aa0, bw, acc[of][0]);
      acc[of][1] = mfma16(aa1, bw, acc[of][1]);
    }
  }

  if (typ < 2){
    ushort (*Cl)[264] = (ushort(*)[264])SB;
    float scl = (typ == 0) ? SCL2 : 1.f;
    #pragma unroll
    for (int of = 0; of < 4; ++of){
      int ol = wid*64 + of*16 + l15;
      float bias = bqkv[typ*256 + ol];
      #pragma unroll
      for (int mf = 0; mf < 2; ++mf)
        #pragma unroll
        for (int r = 0; r < 4; ++r)
          Cl[mf*16 + g4*4 + r][ol] = f2bf((acc[of][mf][r] + bias) * scl);
    }
    __syncthreads();
    ushort* basep = (typ == 0) ? Qf : Kf;
    #pragma unroll
    for (int j = 0; j < 4; ++j){
      int u = t + j*256;
      int h = u >> 8, r = u & 255, dsub = r >> 6, ln = r & 63, h2 = ln >> 5, p31 = ln & 31;
      int row = (typ == 0) ? p31 : ((p31 & 19) | ((p31 & 4) << 1) | ((p31 & 8) >> 1));
      uint4 v = *(const uint4*)&Cl[row][h*64 + dsub*16 + h2*8];
      *(uint4*)(basep + ((size_t)(b*4 + h))*262144 + nt*2048 + dsub*512 + ln*8) = v;
    }
  } else {
    ushort (*Cl_T)[40] = (ushort(*)[40])SB;
    #pragma unroll
    for (int of = 0; of < 4; ++of){
      int ol = wid*64 + of*16 + l15;
      float bias = bqkv[512 + ol];
      #pragma unroll
      for (int mf = 0; mf < 2; ++mf){
        uint2 w2 = make_uint2(pk2bf(acc[of][mf][0]+bias, acc[of][mf][1]+bias),
                              pk2bf(acc[of][mf][2]+bias, acc[of][mf][3]+bias));
        *(uint2*)&Cl_T[ol][mf*16 + g4*4] = w2;
      }
    }
    __syncthreads();
    #pragma unroll
    for (int j = 0; j < 4; ++j){
      int u = t + j*256;
      int h = u >> 8, r = u & 255, dt = r >> 7, r2 = r & 127;
      int c4h = r2 >> 5, p31 = r2 & 31, h2 = c4h & 1, c4loc = c4h >> 1;
      int ln = h2*32 + p31, n0 = c4loc*16 + h2*8;
      uint4 v = *(const uint4*)&Cl_T[h*64 + dt*32 + p31][n0];
      *(uint4*)(Vf + ((size_t)(b*4 + h))*262144 + (size_t)(nt >> 1)*4096
                   + dt*2048 + ((nt & 1)*2 + c4loc)*512 + ln*8) = v;
    }
  }
}

// ---------------- flash attention: LDS-shared K/V tiles, frag layout ----------
// grid 8bh * 32qb * SPLIT x 256 (4 waves x 32q; block shares 64-kv tiles via LDS,
// double-buffered, reg-staged (T14), 1 barrier/iter). bh pinned per XCD.
template<int SPLIT>
__global__ __launch_bounds__(256, 3) void k_attn(const ushort* Qf, const ushort* Kf,
                                                 const ushort* Vf, ushort* Opart, float2* ML){
  __shared__ ushort Kl[2][4096];
  __shared__ ushort Vl[2][4096];
  int bh = blockIdx.x & 7;
  int within = blockIdx.x >> 3;              // [0, 32*SPLIT)
  int sp = within >> 5, qb = within & 31;
  int t = threadIdx.x, wid = t >> 6, l = t & 63, l31 = l & 31, hi = l >> 5;
  int qt = qb*4 + wid;                       // 32-row q tile index [0,128)

  const ushort* Qg = Qf + (size_t)bh*262144 + qt*2048 + l*8;
  const ushort* Kt = Kf + (size_t)bh*262144;
  const ushort* Vt = Vf + (size_t)bh*262144;

  bf16x8 qf[4];
  #pragma unroll
  for (int dsub = 0; dsub < 4; ++dsub)
    qf[dsub] = *(const bf16x8*)(Qg + dsub*512);

  f32x16 o[2];   // [dt]  O^T[d][q]
  #pragma unroll
  for (int dt = 0; dt < 2; ++dt)
    #pragma unroll
    for (int r = 0; r < 16; ++r) o[dt][r] = 0.f;
  float m_s = -INFINITY, l_s = 0.f;

  const int nIt = 64 / SPLIT;
  const int kb0 = sp * nIt;

  // prologue: stage tile kb0 -> buf0 (contiguous 8KB memcpys; frag layout is linear)
  {
    const ushort* Ks = Kt + (size_t)kb0*4096;
    const ushort* Vs = Vt + (size_t)kb0*4096;
    uint4 a0 = *(const uint4*)(Ks + t*8);
    uint4 a1 = *(const uint4*)(Ks + 2048 + t*8);
    uint4 a2 = *(const uint4*)(Vs + t*8);
    uint4 a3 = *(const uint4*)(Vs + 2048 + t*8);
    *(uint4*)&Kl[0][t*8] = a0; *(uint4*)&Kl[0][2048 + t*8] = a1;
    *(uint4*)&Vl[0][t*8] = a2; *(uint4*)&Vl[0][2048 + t*8] = a3;
  }
  __syncthreads();

  for (int it = 0; it < nIt; ++it){
    int cur = it & 1;
    bool more = (it + 1 < nIt);
    uint4 sk0, sk1, sv0, sv1;
    if (more){   // issue next-tile loads early; they land during compute
      const ushort* Ks = Kt + (size_t)(kb0 + it + 1)*4096;
      const ushort* Vs = Vt + (size_t)(kb0 + it + 1)*4096;
      sk0 = *(const uint4*)(Ks + t*8);
      sk1 = *(const uint4*)(Ks + 2048 + t*8);
      sv0 = *(const uint4*)(Vs + t*8);
      sv1 = *(const uint4*)(Vs + 2048 + t*8);
    }

    // QK: S^T[kv][q]  (exp2 domain; Q pre-scaled)
    f32x16 s[2];
    __builtin_amdgcn_s_setprio(1);
    #pragma unroll
    for (int kt = 0; kt < 2; ++kt){
      f32x16 acc;
      #pragma unroll
      for (int r = 0; r < 16; ++r) acc[r] = 0.f;
      #pragma unroll
      for (int dsub = 0; dsub < 4; ++dsub){
        bf16x8 kf = *(const bf16x8*)&Kl[cur][(kt*4 + dsub)*512 + l*8];
        acc = mfma32(kf, qf[dsub], acc);
      }
      s[kt] = acc;
    }
    __builtin_amdgcn_s_setprio(0);

    // softmax (q lane-local; only cross-lane partner is l^32)
    f32x16 mx = s[0];
    #pragma unroll
    for (int r = 0; r < 16; ++r) mx[r] = fmaxf(mx[r], s[1][r]);
    #pragma unroll
    for (int off = 8; off > 0; off >>= 1)
      #pragma unroll
      for (int r = 0; r < off; ++r) mx[r] = fmaxf(mx[r], mx[r + off]);
    float vm = fmaxf(mx[0], __shfl_xor(mx[0], 32));

    if (__any(vm > m_s + 8.f)){
      float mn = fmaxf(m_s, vm);
      float a = __builtin_amdgcn_exp2f(m_s - mn);
      m_s = mn; l_s *= a;
      #pragma unroll
      for (int dt = 0; dt < 2; ++dt)
        #pragma unroll
        for (int r = 0; r < 16; ++r) o[dt][r] *= a;
    }
    {
      float r0 = 0.f, r1 = 0.f, r2 = 0.f, r3 = 0.f;
      #pragma unroll
      for (int kt = 0; kt < 2; ++kt)
        #pragma unroll
        for (int r = 0; r < 16; r += 4){
          float e0 = __builtin_amdgcn_exp2f(s[kt][r+0] - m_s);
          float e1 = __builtin_amdgcn_exp2f(s[kt][r+1] - m_s);
          float e2 = __builtin_amdgcn_exp2f(s[kt][r+2] - m_s);
          float e3 = __builtin_amdgcn_exp2f(s[kt][r+3] - m_s);
          s[kt][r+0] = e0; s[kt][r+1] = e1;
          s[kt][r+2] = e2; s[kt][r+3] = e3;
          r0 += e0; r1 += e1; r2 += e2; r3 += e3;
        }
      float rr = (r0 + r1) + (r2 + r3);
      rr += __shfl_xor(rr, 32);
      l_s += rr;
    }

    // P -> bf16 B-frags (in-lane thanks to baked K-row permutation)
    bf16x8 pf[2][2];   // [kt][ks]
    #pragma unroll
    for (int kt = 0; kt < 2; ++kt)
      #pragma unroll
      for (int ks = 0; ks < 2; ++ks){
        u32x4 w;
        #pragma unroll
        for (int c = 0; c < 4; ++c)
          w[c] = pk2bf(s[kt][8*ks + 2*c], s[kt][8*ks + 2*c + 1]);
        pf[kt][ks] = __builtin_bit_cast(bf16x8, w);
      }

    // PV: O^T[d][q]
    __builtin_amdgcn_s_setprio(1);
    #pragma unroll
    for (int dt = 0; dt < 2; ++dt)
      #pragma unroll
      for (int kt = 0; kt < 2; ++kt)
        #pragma unroll
        for (int ks = 0; ks < 2; ++ks){
          bf16x8 vf = *(const bf16x8*)&Vl[cur][(dt*4 + kt*2 + ks)*512 + l*8];
          o[dt] = mfma32(vf, pf[kt][ks], o[dt]);
        }
    __builtin_amdgcn_s_setprio(0);

    if (more){   // compiler inserts vmcnt waits for the staged loads
      *(uint4*)&Kl[cur^1][t*8] = sk0; *(uint4*)&Kl[cur^1][2048 + t*8] = sk1;
      *(uint4*)&Vl[cur^1][t*8] = sv0; *(uint4*)&Vl[cur^1][2048 + t*8] = sv1;
    }
    __syncthreads();
  }

  // epilogue: raw partial O [pw][32n][64d] + (m,l)
  int pw = (bh*SPLIT + sp)*128 + qt;
  if (hi == 0) ML[(size_t)pw*32 + l31] = make_float2(m_s, l_s);
  ushort* dst = Opart + (size_t)pw*2048;
  #pragma unroll
  for (int dt = 0; dt < 2; ++dt)
    #pragma unroll
    for (int rq = 0; rq < 4; ++rq){
      int d0 = dt*32 + rq*8 + 4*hi;
      uint2 w = make_uint2(pk2bf(o[dt][rq*4+0], o[dt][rq*4+1]),
                           pk2bf(o[dt][rq*4+2], o[dt][rq*4+3]));
      *(uint2*)(dst + (size_t)l31*64 + d0) = w;
    }
}

// ---------------- fused combine + proj GEMM + bias + residual ----------------
// grid (128 nt-of-32, 2 b) x 512 (8 waves)
template<int SPLIT>
__global__ __launch_bounds__(512) void k_cproj(const ushort* Opart, const float2* ML,
                                               const ushort* wpb, const float* bproj,
                                               const float* x, float* out){
  __shared__ ushort A[32][264];
  int nt = blockIdx.x, b = blockIdx.y;
  int t = threadIdx.x;

  // combine: n_local = t>>4 (32 rows), dpos = (t&15)*16 (256 cols / 16 per thread)
  {
    int n_local = t >> 4, dpos = (t & 15) * 16;
    int h = dpos >> 6, dd = dpos & 63;
    int bh = b*4 + h;
    float2 mls[SPLIT];
    float m = -INFINITY;
    #pragma unroll
    for (int sp = 0; sp < SPLIT; ++sp){
      mls[sp] = ML[((size_t)((bh*SPLIT + sp)*128 + nt))*32 + n_local];
      m = fmaxf(m, mls[sp].x);
    }
    float den = 0.f, w[SPLIT];
    #pragma unroll
    for (int sp = 0; sp < SPLIT; ++sp){
      w[sp] = __builtin_amdgcn_exp2f(mls[sp].x - m);
      den += mls[sp].y * w[sp];
    }
    float inv = 1.f / den;
    float vals[16];
    #pragma unroll
    for (int j = 0; j < 16; ++j) vals[j] = 0.f;
    #pragma unroll
    for (int sp = 0; sp < SPLIT; ++sp){
      const ushort* src = Opart + ((size_t)((bh*SPLIT + sp)*128 + nt))*2048 + (size_t)n_local*64 + dd;
      uint4 a0 = *(const uint4*)src;
      uint4 a1 = *(const uint4*)(src + 8);
      float f = w[sp] * inv;
      #pragma unroll
      for (int j = 0; j < 8; ++j) vals[j]     += bf2f(((const ushort*)&a0)[j]) * f;
      #pragma unroll
      for (int j = 0; j < 8; ++j) vals[j + 8] += bf2f(((const ushort*)&a1)[j]) * f;
    }
    uint32_t pk[8];
    #pragma unroll
    for (int j = 0; j < 8; ++j) pk[j] = pk2bf(vals[2*j], vals[2*j+1]);
    *(uint4*)&A[n_local][dpos]     = make_uint4(pk[0], pk[1], pk[2], pk[3]);
    *(uint4*)&A[n_local][dpos + 8] = make_uint4(pk[4], pk[5], pk[6], pk[7]);
  }
  __syncthreads();

  // GEMM: 8 waves x 32o each
  int lane = t & 63, wid = t >> 6, l15 = lane & 15, g4 = lane >> 4;
  f32x4 acc[2][2];   // [of][mf]
  #pragma unroll
  for (int of = 0; of < 2; ++of)
    #pragma unroll
    for (int mf = 0; mf < 2; ++mf) acc[of][mf] = (f32x4){0.f,0.f,0.f,0.f};

  #pragma unroll
  for (int ks = 0; ks < 8; ++ks){
    bf16x8 aa0 = *(const bf16x8*)&A[l15][ks*32 + g4*8];
    bf16x8 aa1 = *(const bf16x8*)&A[16 + l15][ks*32 + g4*8];
    #pragma unroll
    for (int of = 0; of < 2; ++of){
      int o = wid*32 + of*16 + l15;
      bf16x8 bw = *(const bf16x8*)(wpb + (size_t)o*256 + ks*32 + g4*8);
      acc[of][0] = mfma16(aa0, bw, acc[of][0]);
      acc[of][1] = mfma16(aa1, bw, acc[of][1]);
    }
  }

  #pragma unroll
  for (int of = 0; of < 2; ++of){
    int o = wid*32 + of*16 + l15;
    float bias = bproj[o];
    size_t cbase = ((size_t)b*256 + o)*4096;
    #pragma unroll
    for (int mf = 0; mf < 2; ++mf){
      int n0 = nt*32 + mf*16 + g4*4;
      f32x4 res = *(const f32x4*)(x + cbase + n0);
      f32x4 ov;
      #pragma unroll
      for (int r = 0; r < 4; ++r) ov[r] = acc[of][mf][r] + bias + res[r];
      *(f32x4*)(out + cbase + n0) = ov;
    }
  }
}

extern "C" void kernel_launch(void* const* d_in, const int* in_sizes, int n_in,
                              void* d_out, int out_size, void* d_ws, size_t ws_size,
                              hipStream_t stream) {
  const float* x     = (const float*)d_in[0];
  const float* gamma = (const float*)d_in[1];
  const float* beta  = (const float*)d_in[2];
  const float* wqkv  = (const float*)d_in[3];
  const float* bqkv  = (const float*)d_in[4];
  const float* wproj = (const float*)d_in[5];
  const float* bproj = (const float*)d_in[6];
  float* out = (float*)d_out;

  const size_t MiB = 1024*1024;
  char* ws = (char*)d_ws;
  float2* part   = (float2*)(ws + 0);            // 8 KB
  ushort* wq_b   = (ushort*)(ws + 16384);        // 384 KB
  ushort* wp_b   = (ushort*)(ws + 409600);       // 128 KB
  ushort* Qf     = (ushort*)(ws + 1*MiB);        // 4 MiB  frag layout (pre-scaled)
  ushort* Kf     = (ushort*)(ws + 5*MiB);        // 4 MiB  frag layout (rows permuted)
  ushort* Vf     = (ushort*)(ws + 9*MiB);        // 4 MiB  frag layout
  ushort* Xn     = (ushort*)(ws + 13*MiB);       // 4 MiB  [b][n][c] (dead after k_qkv)
  ushort* Opart  = (ushort*)(ws + 13*MiB);       // 4*SPLIT MiB, reuses Xn region

  int split = (ws_size >= 31*MiB) ? 4 : 2;
  float2* ML = (float2*)(ws + (13 + 4*(size_t)split)*MiB);

  k_pg  <<<1792, 256, 0, stream>>>(wqkv, wproj, x, wq_b, wp_b, part);
  k_norm<<<dim3(64,4,2), 256, 0, stream>>>(x, gamma, beta, part, Xn);
  k_qkv <<<dim3(128,3,2), 256, 0, stream>>>(Xn, wq_b, bqkv, Qf, Kf, Vf);
  if (split == 4){
    k_attn<4><<<1024, 256, 0, stream>>>(Qf, Kf, Vf, Opart, ML);
    k_cproj<4><<<dim3(128,2), 512, 0, stream>>>(Opart, ML, wp_b, bproj, x, out);
  } else {
    k_attn<2><<<512, 256, 0, stream>>>(Qf, Kf, Vf, Opart, ML);
    k_cproj<2><<<dim3(128,2), 512, 0, stream>>>(Opart, ML, wp_b, bproj, x, out);
  }
}